// Round 9
// baseline (281.895 us; speedup 1.0000x reference)
//
#include <hip/hip_runtime.h>
#include <hip/hip_bf16.h>

// SDPA B=2 H=16 S=2048 D=64, outputs (out, attn) f32.
// TWO KERNELS, each 256-thread (4-wave) blocks, 64-row Q tiles, grid 1024:
//   4 independent blocks/CU (4 barrier domains) -> decorrelated stalls.
// Kernel A (sumexp): swapped QK^T (s = mfma(K,Q)), fixed-C softmax (C=0),
//   lane-local row sums; stashes -log(l) at out[row][0] (kernel B's epilogue
//   overwrites the stash after reading it once at entry -> race-free).
// Kernel B (main): recompute scores, nt attn stores, PV via K=16 MFMA whose
//   B-frag IS the lane's p-quad (no P LDS round-trip).
// Q pre-scaled 1/8 (exact); 1/l folded into exp arg as ln.
// id%8 = bh%8 -> all q-tiles of a (b,h) share an XCD L2 for K/V.

#define S_LEN 2048
#define DH 64
#define QT 64
#define NCH (S_LEN / 64)

typedef __attribute__((ext_vector_type(8))) short  s16x8;
typedef __attribute__((ext_vector_type(4))) short  s16x4;
typedef __attribute__((ext_vector_type(8))) __bf16 bf16x8;
typedef __attribute__((ext_vector_type(4))) float  f32x4;
typedef __attribute__((ext_vector_type(2))) unsigned int u32x2;

__device__ __forceinline__ short f2bf(float x) {
    __hip_bfloat16 h = __float2bfloat16(x);   // RNE
    return *reinterpret_cast<short*>(&h);
}
__device__ __forceinline__ unsigned pack2(float a, float b) {
    return (unsigned)(unsigned short)f2bf(a) | ((unsigned)(unsigned short)f2bf(b) << 16);
}
__device__ __forceinline__ bf16x8 ldfrag(const short* p) {
    s16x8 t = *(const s16x8*)p;               // ds_read_b128
    return __builtin_bit_cast(bf16x8, t);
}
// XOR swizzle within a [rows][64] bf16 tile (G4: break 128B-stride bank collisions).
__device__ __forceinline__ int SW(int r, int c) { return r * 64 + (c ^ ((r & 7) << 3)); }

// ---------------- Kernel A: per-row -log(sum exp) ----------------
__global__ __launch_bounds__(256, 4) void sumexp_kernel(
    const float* __restrict__ q, const float* __restrict__ k,
    const int* __restrict__ mask, float* __restrict__ out)
{
    __shared__ __align__(16) short shK[2][64 * 64];   // 16 KB dbuf [key][d]
    __shared__ char shMask[S_LEN];                    // 2 KB

    const int tid  = threadIdx.x;
    const int lane = tid & 63;
    const int w    = tid >> 6;    // 0..3, owns q rows w*16..w*16+15
    const int l15  = lane & 15;
    const int lg   = lane >> 4;

    const int id = blockIdx.x;
    const int bh = id & 31;
    const int q0 = (id >> 5) * QT;
    const int b  = bh >> 4;

    const float* qbase = q + ((size_t)bh * S_LEN + q0) * DH;
    const float* kbase = k + (size_t)bh * S_LEN * DH;

    for (int i = tid; i < S_LEN; i += 256)
        shMask[i] = (char)(mask[b * S_LEN + i] != 0);

    const int qrow = w * 16 + l15;
    bf16x8 qf0, qf1;
    {
        const float* qp = qbase + qrow * DH + 8 * lg;
        const float4 a0 = *(const float4*)(qp);
        const float4 a1 = *(const float4*)(qp + 4);
        const float4 b0 = *(const float4*)(qp + 32);
        const float4 b1 = *(const float4*)(qp + 36);
        s16x8 t0, t1;
        t0[0]=f2bf(a0.x*0.125f); t0[1]=f2bf(a0.y*0.125f); t0[2]=f2bf(a0.z*0.125f); t0[3]=f2bf(a0.w*0.125f);
        t0[4]=f2bf(a1.x*0.125f); t0[5]=f2bf(a1.y*0.125f); t0[6]=f2bf(a1.z*0.125f); t0[7]=f2bf(a1.w*0.125f);
        t1[0]=f2bf(b0.x*0.125f); t1[1]=f2bf(b0.y*0.125f); t1[2]=f2bf(b0.z*0.125f); t1[3]=f2bf(b0.w*0.125f);
        t1[4]=f2bf(b1.x*0.125f); t1[5]=f2bf(b1.y*0.125f); t1[6]=f2bf(b1.z*0.125f); t1[7]=f2bf(b1.w*0.125f);
        qf0 = __builtin_bit_cast(bf16x8, t0);
        qf1 = __builtin_bit_cast(bf16x8, t1);
    }

    const int krow = tid >> 2;               // 0..63
    const int kd0  = (tid & 3) * 16;
    float4 ka0, ka1, ka2, ka3;
    auto loadK = [&](int c0) {
        const float* src = kbase + (size_t)(c0 + krow) * DH + kd0;
        ka0 = *(const float4*)(src);
        ka1 = *(const float4*)(src + 4);
        ka2 = *(const float4*)(src + 8);
        ka3 = *(const float4*)(src + 12);
    };
    auto writeK = [&](short* dst) {
        s16x8 v0, v1;
        v0[0]=f2bf(ka0.x); v0[1]=f2bf(ka0.y); v0[2]=f2bf(ka0.z); v0[3]=f2bf(ka0.w);
        v0[4]=f2bf(ka1.x); v0[5]=f2bf(ka1.y); v0[6]=f2bf(ka1.z); v0[7]=f2bf(ka1.w);
        v1[0]=f2bf(ka2.x); v1[1]=f2bf(ka2.y); v1[2]=f2bf(ka2.z); v1[3]=f2bf(ka2.w);
        v1[4]=f2bf(ka3.x); v1[5]=f2bf(ka3.y); v1[6]=f2bf(ka3.z); v1[7]=f2bf(ka3.w);
        *(s16x8*)&dst[SW(krow, kd0)]     = v0;
        *(s16x8*)&dst[SW(krow, kd0 + 8)] = v1;
    };

    loadK(0);
    writeK(shK[0]);
    __syncthreads();

    float lacc = 0.f;
    for (int t = 0; t < NCH; ++t) {
        const int cur = t & 1;
        if (t + 1 < NCH) loadK((t + 1) * 64);
        __syncthreads();
        const short* K = shK[cur];
        const int c0 = t * 64;
        f32x4 s[4] = {{0,0,0,0},{0,0,0,0},{0,0,0,0},{0,0,0,0}};
#pragma unroll
        for (int ct = 0; ct < 4; ++ct) {
            const int kc = ct * 16 + l15;
            bf16x8 kf = ldfrag(&K[SW(kc, 8 * lg)]);
            s[ct] = __builtin_amdgcn_mfma_f32_16x16x32_bf16(kf, qf0, s[ct], 0, 0, 0);
            kf = ldfrag(&K[SW(kc, 32 + 8 * lg)]);
            s[ct] = __builtin_amdgcn_mfma_f32_16x16x32_bf16(kf, qf1, s[ct], 0, 0, 0);
        }
#pragma unroll
        for (int ct = 0; ct < 4; ++ct) {
            const unsigned mw = *(const unsigned*)&shMask[c0 + ct * 16 + lg * 4];
#pragma unroll
            for (int r = 0; r < 4; ++r)
                lacc += ((mw >> (8 * r)) & 1u) ? __expf(s[ct][r]) : 0.f;
        }
        if (t + 1 < NCH) writeK(shK[cur ^ 1]);
    }
    lacc += __shfl_xor(lacc, 16);
    lacc += __shfl_xor(lacc, 32);
    if (lg == 0)    // stash -log(l) at out[row][0]; kernel B overwrites later
        out[((size_t)bh * S_LEN + q0 + qrow) * DH] = -__logf(lacc);
}

// ---------------- Kernel B: attn stores + PV ----------------
__global__ __launch_bounds__(256, 4) void sdpa_main_kernel(
    const float* __restrict__ q, const float* __restrict__ k,
    const float* __restrict__ v, const int* __restrict__ mask,
    float* __restrict__ out, float* __restrict__ attn)
{
    __shared__ __align__(16) short shK[2][64 * 64];    // 16 KB dbuf [key][d]
    __shared__ __align__(16) short shVt[2][64 * 64];   // 16 KB dbuf [d][key]
    __shared__ char shMask[S_LEN];                     // 2 KB

    const int tid  = threadIdx.x;
    const int lane = tid & 63;
    const int w    = tid >> 6;    // 0..3
    const int l15  = lane & 15;
    const int lg   = lane >> 4;

    const int id = blockIdx.x;
    const int bh = id & 31;
    const int q0 = (id >> 5) * QT;
    const int b  = bh >> 4;

    const float* qbase = q + ((size_t)bh * S_LEN + q0) * DH;
    const float* kbase = k + (size_t)bh * S_LEN * DH;
    const float* vbase = v + (size_t)bh * S_LEN * DH;
    float* attnbh = attn + (size_t)bh * S_LEN * S_LEN;

    const int qrow = w * 16 + l15;
    // read the stash before anything else (own-block epilogue overwrites it)
    const float lnInvl = out[((size_t)bh * S_LEN + q0 + qrow) * DH];

    for (int i = tid; i < S_LEN; i += 256)
        shMask[i] = (char)(mask[b * S_LEN + i] != 0);

    bf16x8 qf0, qf1;
    {
        const float* qp = qbase + qrow * DH + 8 * lg;
        const float4 a0 = *(const float4*)(qp);
        const float4 a1 = *(const float4*)(qp + 4);
        const float4 b0 = *(const float4*)(qp + 32);
        const float4 b1 = *(const float4*)(qp + 36);
        s16x8 t0, t1;
        t0[0]=f2bf(a0.x*0.125f); t0[1]=f2bf(a0.y*0.125f); t0[2]=f2bf(a0.z*0.125f); t0[3]=f2bf(a0.w*0.125f);
        t0[4]=f2bf(a1.x*0.125f); t0[5]=f2bf(a1.y*0.125f); t0[6]=f2bf(a1.z*0.125f); t0[7]=f2bf(a1.w*0.125f);
        t1[0]=f2bf(b0.x*0.125f); t1[1]=f2bf(b0.y*0.125f); t1[2]=f2bf(b0.z*0.125f); t1[3]=f2bf(b0.w*0.125f);
        t1[4]=f2bf(b1.x*0.125f); t1[5]=f2bf(b1.y*0.125f); t1[6]=f2bf(b1.z*0.125f); t1[7]=f2bf(b1.w*0.125f);
        qf0 = __builtin_bit_cast(bf16x8, t0);
        qf1 = __builtin_bit_cast(bf16x8, t1);
    }

    // K staging: 64 rows x 64 d
    const int krow = tid >> 2;
    const int kd0  = (tid & 3) * 16;
    float4 ka0, ka1, ka2, ka3;
    auto loadK = [&](int c0) {
        const float* src = kbase + (size_t)(c0 + krow) * DH + kd0;
        ka0 = *(const float4*)(src);
        ka1 = *(const float4*)(src + 4);
        ka2 = *(const float4*)(src + 8);
        ka3 = *(const float4*)(src + 12);
    };
    auto writeK = [&](short* dst) {
        s16x8 v0, v1;
        v0[0]=f2bf(ka0.x); v0[1]=f2bf(ka0.y); v0[2]=f2bf(ka0.z); v0[3]=f2bf(ka0.w);
        v0[4]=f2bf(ka1.x); v0[5]=f2bf(ka1.y); v0[6]=f2bf(ka1.z); v0[7]=f2bf(ka1.w);
        v1[0]=f2bf(ka2.x); v1[1]=f2bf(ka2.y); v1[2]=f2bf(ka2.z); v1[3]=f2bf(ka2.w);
        v1[4]=f2bf(ka3.x); v1[5]=f2bf(ka3.y); v1[6]=f2bf(ka3.z); v1[7]=f2bf(ka3.w);
        *(s16x8*)&dst[SW(krow, kd0)]     = v0;
        *(s16x8*)&dst[SW(krow, kd0 + 8)] = v1;
    };

    // V staging: thread owns 4 rows (vr0..+3) x 4 d (vdg*4..+3), writes Vt[d][k]
    const int vdg = tid >> 4;                // 0..15
    const int vr0 = (tid & 15) * 4;          // 0..60
    float4 vv0, vv1, vv2, vv3;
    auto loadV = [&](int c0) {
        const float* src = vbase + (size_t)(c0 + vr0) * DH + vdg * 4;
        vv0 = *(const float4*)(src);
        vv1 = *(const float4*)(src + DH);
        vv2 = *(const float4*)(src + 2 * DH);
        vv3 = *(const float4*)(src + 3 * DH);
    };
    auto writeVt = [&](short* dst) {
        const float r0v[4] = {vv0.x, vv0.y, vv0.z, vv0.w};
        const float r1v[4] = {vv1.x, vv1.y, vv1.z, vv1.w};
        const float r2v[4] = {vv2.x, vv2.y, vv2.z, vv2.w};
        const float r3v[4] = {vv3.x, vv3.y, vv3.z, vv3.w};
#pragma unroll
        for (int i = 0; i < 4; ++i) {
            const int d = vdg * 4 + i;
            u32x2 pk;
            pk[0] = pack2(r0v[i], r1v[i]);
            pk[1] = pack2(r2v[i], r3v[i]);
            *(u32x2*)&dst[SW(d, vr0)] = pk;   // 8B-aligned: swizzle flips bits>=3
        }
    };

    loadK(0);
    loadV(0);
    writeK(shK[0]);
    writeVt(shVt[0]);
    __syncthreads();

    f32x4 oacc[4] = {{0,0,0,0},{0,0,0,0},{0,0,0,0},{0,0,0,0}};

    for (int t = 0; t < NCH; ++t) {
        const int cur = t & 1;
        if (t + 1 < NCH) { loadK((t + 1) * 64); loadV((t + 1) * 64); }
        __syncthreads();
        const short* K  = shK[cur];
        const short* Vt = shVt[cur];
        const int c0 = t * 64;
        float* abase = attnbh + (size_t)(q0 + qrow) * S_LEN + c0;

        // phase 1: all 4 score tiles (independent chains)
        f32x4 s[4] = {{0,0,0,0},{0,0,0,0},{0,0,0,0},{0,0,0,0}};
#pragma unroll
        for (int ct = 0; ct < 4; ++ct) {
            const int kc = ct * 16 + l15;
            bf16x8 kf = ldfrag(&K[SW(kc, 8 * lg)]);
            s[ct] = __builtin_amdgcn_mfma_f32_16x16x32_bf16(kf, qf0, s[ct], 0, 0, 0);
            kf = ldfrag(&K[SW(kc, 32 + 8 * lg)]);
            s[ct] = __builtin_amdgcn_mfma_f32_16x16x32_bf16(kf, qf1, s[ct], 0, 0, 0);
        }
        // phase 2: exp + mask, nt store, pack p-quads
        s16x4 pf[4];
#pragma unroll
        for (int ct = 0; ct < 4; ++ct) {
            const unsigned mw = *(const unsigned*)&shMask[c0 + ct * 16 + lg * 4];
            f32x4 p;
#pragma unroll
            for (int r = 0; r < 4; ++r)
                p[r] = ((mw >> (8 * r)) & 1u) ? __expf(s[ct][r] + lnInvl) : 0.f;
            __builtin_nontemporal_store(p, (f32x4*)(abase + ct * 16 + lg * 4));
            u32x2 pk;
            pk[0] = pack2(p[0], p[1]);
            pk[1] = pack2(p[2], p[3]);
            pf[ct] = __builtin_bit_cast(s16x4, pk);
        }
        // phase 3: PV, 4 independent oacc chains x 4 k-quads (K=16 MFMA)
#pragma unroll
        for (int dt = 0; dt < 4; ++dt) {
#pragma unroll
            for (int ct = 0; ct < 4; ++ct) {
                const s16x4 af = *(const s16x4*)&Vt[SW(dt * 16 + l15, ct * 16 + 4 * lg)];
                oacc[dt] = __builtin_amdgcn_mfma_f32_16x16x16bf16_1k(af, pf[ct], oacc[dt], 0, 0, 0);
            }
        }
        if (t + 1 < NCH) { writeK(shK[cur ^ 1]); writeVt(shVt[cur ^ 1]); }
    }

    // epilogue: out[q][d] (overwrites the lnInvl stash at d=0)
    float* obase = out + ((size_t)bh * S_LEN + q0 + qrow) * DH;
#pragma unroll
    for (int dt = 0; dt < 4; ++dt)
        __builtin_nontemporal_store(oacc[dt], (f32x4*)(obase + dt * 16 + lg * 4));
}

extern "C" void kernel_launch(void* const* d_in, const int* in_sizes, int n_in,
                              void* d_out, int out_size, void* d_ws, size_t ws_size,
                              hipStream_t stream)
{
    const float* q    = (const float*)d_in[0];
    const float* k    = (const float*)d_in[1];
    const float* v    = (const float*)d_in[2];
    const int*   mask = (const int*)d_in[3];
    float* out  = (float*)d_out;
    float* attn = out + (size_t)2 * 16 * 2048 * 64;   // (out, attn) concatenated

    dim3 grid((S_LEN / QT) * 32);   // 1024 blocks, id%8 = bh%8 (XCD locality)
    sumexp_kernel<<<grid, dim3(256), 0, stream>>>(q, k, mask, out);
    sdpa_main_kernel<<<grid, dim3(256), 0, stream>>>(q, k, v, mask, out, attn);
}

// Round 10
// 274.110 us; speedup vs baseline: 1.0284x; 1.0284x over previous
//
#include <hip/hip_runtime.h>
#include <hip/hip_bf16.h>

// SDPA B=2 H=16 S=2048 D=64, outputs (out, attn) f32.
// Two-pass flash, ONE kernel. QT=64 rows, 512 threads, grid 1024:
//   8 waves = 4 row-bands (wr) x 2 k-column halves (wc); each wave 16 rows x
//   32 cols per 64-col chunk. LDS 34KB -> 4 blocks/CU = 32 waves/CU (2x R6).
// SWAPPED QK^T (s = mfma(K, Q)): lane holds (q=l15, k quad 4*lg+r).
// PV via mfma_f32_16x16x16_bf16 (K=16): B-frag IS the lane's p-quad.
// Cross-wave merges: l via tiny LDS exchange after pass A; oacc via 16KB LDS
//   (aliases dead shK) at epilogue.
// Fixed-C softmax (C=0, scores bounded); Q pre-scaled 1/8; 1/l folded as ln.
// 1D grid, id%8 = bh%8 -> all q-tiles of a (b,h) share an XCD L2 for K/V.

#define S_LEN 2048
#define DH 64
#define QT 64
#define NCH (S_LEN / 64)

typedef __attribute__((ext_vector_type(8))) short  s16x8;
typedef __attribute__((ext_vector_type(4))) short  s16x4;
typedef __attribute__((ext_vector_type(8))) __bf16 bf16x8;
typedef __attribute__((ext_vector_type(4))) float  f32x4;
typedef __attribute__((ext_vector_type(2))) unsigned int u32x2;

__device__ __forceinline__ short f2bf(float x) {
    __hip_bfloat16 h = __float2bfloat16(x);   // RNE
    return *reinterpret_cast<short*>(&h);
}
__device__ __forceinline__ unsigned pack2(float a, float b) {
    return (unsigned)(unsigned short)f2bf(a) | ((unsigned)(unsigned short)f2bf(b) << 16);
}
__device__ __forceinline__ bf16x8 ldfrag(const short* p) {
    s16x8 t = *(const s16x8*)p;               // ds_read_b128
    return __builtin_bit_cast(bf16x8, t);
}
// XOR swizzle within a [rows][64] bf16 tile (G4: break 128B-stride bank collisions).
__device__ __forceinline__ int SW(int r, int c) { return r * 64 + (c ^ ((r & 7) << 3)); }

__global__ __launch_bounds__(512, 8) void sdpa_kernel(
    const float* __restrict__ q, const float* __restrict__ k,
    const float* __restrict__ v, const int* __restrict__ mask,
    float* __restrict__ out, float* __restrict__ attn)
{
    __shared__ __align__(16) short shK[2][64 * 64];    // 16 KB dbuf [key][d]
    __shared__ __align__(16) short shVt[2][64 * 64];   // 16 KB dbuf [d][key]
    __shared__ char  shMask[S_LEN];                    // 2 KB
    __shared__ float shL[2][4][16];                    // 128 B

    const int tid  = threadIdx.x;
    const int lane = tid & 63;
    const int w    = tid >> 6;    // 0..7
    const int wr   = w >> 1;      // 0..3 row band
    const int wc   = w & 1;       // 0..1 k-column half
    const int l15  = lane & 15;   // q row within band
    const int lg   = lane >> 4;   // 0..3

    const int id = blockIdx.x;    // id%8 = bh%8 -> XCD locality for K/V
    const int bh = id & 31;
    const int q0 = (id >> 5) * QT;
    const int b  = bh >> 4;

    const float* qbase = q + ((size_t)bh * S_LEN + q0) * DH;
    const float* kbase = k + (size_t)bh * S_LEN * DH;
    const float* vbase = v + (size_t)bh * S_LEN * DH;
    float* attnbh = attn + (size_t)bh * S_LEN * S_LEN;

    // ---- mask bytes to LDS ----
    for (int i = tid; i < S_LEN; i += 512)
        shMask[i] = (char)(mask[b * S_LEN + i] != 0);

    // ---- Q fragments straight to registers (scaled 1/8, bf16) ----
    const int qrow = wr * 16 + l15;
    bf16x8 qf0, qf1;
    {
        const float* qp = qbase + qrow * DH + 8 * lg;
        const float4 a0 = *(const float4*)(qp);
        const float4 a1 = *(const float4*)(qp + 4);
        const float4 b0 = *(const float4*)(qp + 32);
        const float4 b1 = *(const float4*)(qp + 36);
        s16x8 t0, t1;
        t0[0]=f2bf(a0.x*0.125f); t0[1]=f2bf(a0.y*0.125f); t0[2]=f2bf(a0.z*0.125f); t0[3]=f2bf(a0.w*0.125f);
        t0[4]=f2bf(a1.x*0.125f); t0[5]=f2bf(a1.y*0.125f); t0[6]=f2bf(a1.z*0.125f); t0[7]=f2bf(a1.w*0.125f);
        t1[0]=f2bf(b0.x*0.125f); t1[1]=f2bf(b0.y*0.125f); t1[2]=f2bf(b0.z*0.125f); t1[3]=f2bf(b0.w*0.125f);
        t1[4]=f2bf(b1.x*0.125f); t1[5]=f2bf(b1.y*0.125f); t1[6]=f2bf(b1.z*0.125f); t1[7]=f2bf(b1.w*0.125f);
        qf0 = __builtin_bit_cast(bf16x8, t0);
        qf1 = __builtin_bit_cast(bf16x8, t1);
    }

    // ---- staging helpers (reg-staged: load early, convert+write late) ----
    const int krow = tid >> 3;               // 0..63 (key index in chunk)
    const int kd0  = (tid & 7) * 8;
    auto loadK = [&](int c0, float4& a, float4& bb) {
        const float* src = kbase + (size_t)(c0 + krow) * DH + kd0;
        a  = *(const float4*)(src);
        bb = *(const float4*)(src + 4);
    };
    auto writeK = [&](short* dst, const float4& a, const float4& bb) {
        s16x8 vv;
        vv[0]=f2bf(a.x);  vv[1]=f2bf(a.y);  vv[2]=f2bf(a.z);  vv[3]=f2bf(a.w);
        vv[4]=f2bf(bb.x); vv[5]=f2bf(bb.y); vv[6]=f2bf(bb.z); vv[7]=f2bf(bb.w);
        *(s16x8*)&dst[SW(krow, kd0)] = vv;
    };
    const int vr0 = (tid & 31) * 2;          // 0..62 (even key)
    const int vdg = tid >> 5;                // 0..15 (4 d's each)
    auto loadV = [&](int c0, float4& a, float4& bb) {
        const float* src = vbase + (size_t)(c0 + vr0) * DH + vdg * 4;
        a  = *(const float4*)(src);
        bb = *(const float4*)(src + DH);
    };
    auto writeVt = [&](short* dst, const float4& a, const float4& bb) {
        const float av[4] = {a.x, a.y, a.z, a.w};
        const float bv[4] = {bb.x, bb.y, bb.z, bb.w};
        int* dw = (int*)dst;
#pragma unroll
        for (int i = 0; i < 4; ++i) {
            const int d = vdg * 4 + i;
            dw[(d * 64 + (vr0 ^ ((d & 7) << 3))) >> 1] = (int)pack2(av[i], bv[i]);
        }
    };

    // prologue for pass A: chunk 0 into buffer 0
    float4 ka, kb;
    loadK(0, ka, kb);
    writeK(shK[0], ka, kb);
    __syncthreads();

    // -------- PASS A: row sumexp (fixed C=0); wave covers its 32-col half --------
    float lacc = 0.f;
    for (int t = 0; t < NCH; ++t) {
        const int cur = t & 1;
        if (t + 1 < NCH) loadK((t + 1) * 64, ka, kb);   // issue a chunk early
        __syncthreads();                                 // buf[cur] ready
        const short* K = shK[cur];
        const int c0 = t * 64;
        f32x4 s[2] = {{0,0,0,0},{0,0,0,0}};
#pragma unroll
        for (int ct = 0; ct < 2; ++ct) {
            const int kc = wc * 32 + ct * 16 + l15;
            bf16x8 kf = ldfrag(&K[SW(kc, 8 * lg)]);
            s[ct] = __builtin_amdgcn_mfma_f32_16x16x32_bf16(kf, qf0, s[ct], 0, 0, 0);
            kf = ldfrag(&K[SW(kc, 32 + 8 * lg)]);
            s[ct] = __builtin_amdgcn_mfma_f32_16x16x32_bf16(kf, qf1, s[ct], 0, 0, 0);
        }
#pragma unroll
        for (int ct = 0; ct < 2; ++ct) {
            const unsigned mw = *(const unsigned*)&shMask[c0 + wc * 32 + ct * 16 + lg * 4];
#pragma unroll
            for (int r = 0; r < 4; ++r)
                lacc += ((mw >> (8 * r)) & 1u) ? __expf(s[ct][r]) : 0.f;
        }
        if (t + 1 < NCH) writeK(shK[cur ^ 1], ka, kb);
    }
    lacc += __shfl_xor(lacc, 16);
    lacc += __shfl_xor(lacc, 32);
    if (lg == 0)
        shL[wc][wr][l15] = lacc;
    __syncthreads();
    const float lnInvl = -__logf(shL[0][wr][l15] + shL[1][wr][l15]);

    // -------- PASS B: recompute, write attn (own half), PV accumulate --------
    f32x4 oacc[4] = {{0,0,0,0},{0,0,0,0},{0,0,0,0},{0,0,0,0}};
    float4 va, vb;
    loadK(0, ka, kb);
    loadV(0, va, vb);
    // post-merge barrier passed; all pass-A LDS reads done
    writeK(shK[0], ka, kb);
    writeVt(shVt[0], va, vb);

    for (int t = 0; t < NCH; ++t) {
        const int cur = t & 1;
        if (t + 1 < NCH) { loadK((t + 1) * 64, ka, kb); loadV((t + 1) * 64, va, vb); }
        __syncthreads();
        const short* K  = shK[cur];
        const short* Vt = shVt[cur];
        const int c0 = t * 64;
        float* abase = attnbh + (size_t)(q0 + qrow) * S_LEN + c0 + wc * 32;

        // phase 1: both score tiles (independent chains)
        f32x4 s[2] = {{0,0,0,0},{0,0,0,0}};
#pragma unroll
        for (int ct = 0; ct < 2; ++ct) {
            const int kc = wc * 32 + ct * 16 + l15;
            bf16x8 kf = ldfrag(&K[SW(kc, 8 * lg)]);
            s[ct] = __builtin_amdgcn_mfma_f32_16x16x32_bf16(kf, qf0, s[ct], 0, 0, 0);
            kf = ldfrag(&K[SW(kc, 32 + 8 * lg)]);
            s[ct] = __builtin_amdgcn_mfma_f32_16x16x32_bf16(kf, qf1, s[ct], 0, 0, 0);
        }
        // phase 2: exp + mask, nt store, pack p-quads
        s16x4 pf[2];
#pragma unroll
        for (int ct = 0; ct < 2; ++ct) {
            const unsigned mw = *(const unsigned*)&shMask[c0 + wc * 32 + ct * 16 + lg * 4];
            f32x4 p;
#pragma unroll
            for (int r = 0; r < 4; ++r)
                p[r] = ((mw >> (8 * r)) & 1u) ? __expf(s[ct][r] + lnInvl) : 0.f;
            __builtin_nontemporal_store(p, (f32x4*)(abase + ct * 16 + lg * 4));
            u32x2 pk;
            pk[0] = pack2(p[0], p[1]);
            pk[1] = pack2(p[2], p[3]);
            pf[ct] = __builtin_bit_cast(s16x4, pk);
        }
        // phase 3: PV over own k-half, 4 independent oacc chains (K=16 MFMA)
#pragma unroll
        for (int dt = 0; dt < 4; ++dt) {
#pragma unroll
            for (int ct = 0; ct < 2; ++ct) {
                const s16x4 af = *(const s16x4*)&Vt[SW(dt * 16 + l15, wc * 32 + ct * 16 + 4 * lg)];
                oacc[dt] = __builtin_amdgcn_mfma_f32_16x16x16bf16_1k(af, pf[ct], oacc[dt], 0, 0, 0);
            }
        }
        if (t + 1 < NCH) { writeK(shK[cur ^ 1], ka, kb); writeVt(shVt[cur ^ 1], va, vb); }
    }

    // ---- epilogue: merge oacc across wc via LDS (aliases dead shK), store ----
    __syncthreads();                       // all pass-B LDS reads done
    float* shO = (float*)shK;              // 16 KB
    if (wc == 1) {
#pragma unroll
        for (int dt = 0; dt < 4; ++dt)
#pragma unroll
            for (int r = 0; r < 4; ++r)
                shO[((wr * 4 + dt) * 4 + r) * 64 + lane] = oacc[dt][r];
    }
    __syncthreads();
    if (wc == 0) {
        float* obase = out + ((size_t)bh * S_LEN + q0 + qrow) * DH;
#pragma unroll
        for (int dt = 0; dt < 4; ++dt) {
            f32x4 o;
#pragma unroll
            for (int r = 0; r < 4; ++r)
                o[r] = oacc[dt][r] + shO[((wr * 4 + dt) * 4 + r) * 64 + lane];
            __builtin_nontemporal_store(o, (f32x4*)(obase + dt * 16 + lg * 4));
        }
    }
}

extern "C" void kernel_launch(void* const* d_in, const int* in_sizes, int n_in,
                              void* d_out, int out_size, void* d_ws, size_t ws_size,
                              hipStream_t stream)
{
    const float* q    = (const float*)d_in[0];
    const float* k    = (const float*)d_in[1];
    const float* v    = (const float*)d_in[2];
    const int*   mask = (const int*)d_in[3];
    float* out  = (float*)d_out;
    float* attn = out + (size_t)2 * 16 * 2048 * 64;   // (out, attn) concatenated

    sdpa_kernel<<<dim3((S_LEN / QT) * 32), dim3(512), 0, stream>>>(q, k, v, mask, out, attn);
}

// Round 11
// 168.475 us; speedup vs baseline: 1.6732x; 1.6270x over previous
//
#include <hip/hip_runtime.h>
#include <hip/hip_bf16.h>

// SDPA B=2 H=16 S=2048 D=64, outputs (out, attn) f32.
// Two-pass flash, QT=128 rows, 8 waves x 16 rows, 64-col K/V chunks, 2D grid
// (x=qtile, y=bh) -- the R3 grid that measured 197us / ~4.6 TB/s sustained.
// SWAPPED QK^T (s = mfma(K, Q)): lane holds (q=l15, k quad ct*16+4*lg+r).
// PV via mfma_f32_16x16x16_bf16 (K=16): B-frag IS the lane's p-quad.
// FULL-LINE attn stores: per-wave f32 LDS transpose, then nt f32x4 stores
// where 8 lanes cover one whole 128B line per row (8 rows/instr) -- fixes the
// 64B-half-line write inflation (WRITE_SIZE 711MB vs 554MB ideal in R5/R6).
// Fixed-C softmax (C=0, scores bounded); Q pre-scaled 1/8; 1/l folded as ln.

#define S_LEN 2048
#define DH 64
#define QT 128
#define NCH (S_LEN / 64)

typedef __attribute__((ext_vector_type(8))) short  s16x8;
typedef __attribute__((ext_vector_type(4))) short  s16x4;
typedef __attribute__((ext_vector_type(8))) __bf16 bf16x8;
typedef __attribute__((ext_vector_type(4))) float  f32x4;
typedef __attribute__((ext_vector_type(2))) unsigned int u32x2;

__device__ __forceinline__ short f2bf(float x) {
    __hip_bfloat16 h = __float2bfloat16(x);   // RNE
    return *reinterpret_cast<short*>(&h);
}
__device__ __forceinline__ unsigned pack2(float a, float b) {
    return (unsigned)(unsigned short)f2bf(a) | ((unsigned)(unsigned short)f2bf(b) << 16);
}
__device__ __forceinline__ bf16x8 ldfrag(const short* p) {
    s16x8 t = *(const s16x8*)p;               // ds_read_b128
    return __builtin_bit_cast(bf16x8, t);
}
// XOR swizzles (G4): bf16 [rows][64] tile, and f32 [rows][64] tile.
__device__ __forceinline__ int SW (int r, int c) { return r * 64 + (c ^ ((r & 7) << 3)); }
__device__ __forceinline__ int SWF(int r, int c) { return r * 64 + (c ^ ((r & 7) << 3)); }

__global__ __launch_bounds__(512, 4) void sdpa_kernel(
    const float* __restrict__ q, const float* __restrict__ k,
    const float* __restrict__ v, const int* __restrict__ mask,
    float* __restrict__ out, float* __restrict__ attn)
{
    __shared__ __align__(16) short shK[2][64 * 64];    // 16 KB dbuf [key][d]
    __shared__ __align__(16) short shVt[2][64 * 64];   // 16 KB dbuf [d][key]
    __shared__ __align__(16) float shPT[8][16 * 64];   // 32 KB, per-wave P f32
    __shared__ char shMask[S_LEN];                     // 2 KB

    const int tid  = threadIdx.x;
    const int lane = tid & 63;
    const int w    = tid >> 6;    // 0..7, owns q rows w*16..w*16+15
    const int l15  = lane & 15;   // q row within wave band
    const int lg   = lane >> 4;   // 0..3

    const int bh = blockIdx.y;    // 0..31
    const int q0 = blockIdx.x * QT;
    const int b  = bh >> 4;

    const float* qbase = q + ((size_t)bh * S_LEN + q0) * DH;
    const float* kbase = k + (size_t)bh * S_LEN * DH;
    const float* vbase = v + (size_t)bh * S_LEN * DH;
    float* attnbh = attn + (size_t)bh * S_LEN * S_LEN;

    // ---- mask bytes to LDS ----
    for (int i = tid; i < S_LEN; i += 512)
        shMask[i] = (char)(mask[b * S_LEN + i] != 0);

    // ---- Q fragments straight to registers (scaled 1/8, bf16) ----
    const int qrow = w * 16 + l15;
    bf16x8 qf0, qf1;
    {
        const float* qp = qbase + qrow * DH + 8 * lg;
        const float4 a0 = *(const float4*)(qp);
        const float4 a1 = *(const float4*)(qp + 4);
        const float4 b0 = *(const float4*)(qp + 32);
        const float4 b1 = *(const float4*)(qp + 36);
        s16x8 t0, t1;
        t0[0]=f2bf(a0.x*0.125f); t0[1]=f2bf(a0.y*0.125f); t0[2]=f2bf(a0.z*0.125f); t0[3]=f2bf(a0.w*0.125f);
        t0[4]=f2bf(a1.x*0.125f); t0[5]=f2bf(a1.y*0.125f); t0[6]=f2bf(a1.z*0.125f); t0[7]=f2bf(a1.w*0.125f);
        t1[0]=f2bf(b0.x*0.125f); t1[1]=f2bf(b0.y*0.125f); t1[2]=f2bf(b0.z*0.125f); t1[3]=f2bf(b0.w*0.125f);
        t1[4]=f2bf(b1.x*0.125f); t1[5]=f2bf(b1.y*0.125f); t1[6]=f2bf(b1.z*0.125f); t1[7]=f2bf(b1.w*0.125f);
        qf0 = __builtin_bit_cast(bf16x8, t0);
        qf1 = __builtin_bit_cast(bf16x8, t1);
    }

    // ---- staging helpers (reg-staged: load early, convert+write late) ----
    const int krow = tid >> 3;               // 0..63 (key index in chunk)
    const int kd0  = (tid & 7) * 8;
    auto loadK = [&](int c0, float4& a, float4& bb) {
        const float* src = kbase + (size_t)(c0 + krow) * DH + kd0;
        a  = *(const float4*)(src);
        bb = *(const float4*)(src + 4);
    };
    auto writeK = [&](short* dst, const float4& a, const float4& bb) {
        s16x8 vv;
        vv[0]=f2bf(a.x);  vv[1]=f2bf(a.y);  vv[2]=f2bf(a.z);  vv[3]=f2bf(a.w);
        vv[4]=f2bf(bb.x); vv[5]=f2bf(bb.y); vv[6]=f2bf(bb.z); vv[7]=f2bf(bb.w);
        *(s16x8*)&dst[SW(krow, kd0)] = vv;
    };
    const int vr0 = (tid & 31) * 2;          // 0..62 (even key)
    const int vdg = tid >> 5;                // 0..15 (4 d's each)
    auto loadV = [&](int c0, float4& a, float4& bb) {
        const float* src = vbase + (size_t)(c0 + vr0) * DH + vdg * 4;
        a  = *(const float4*)(src);
        bb = *(const float4*)(src + DH);
    };
    auto writeVt = [&](short* dst, const float4& a, const float4& bb) {
        const float av[4] = {a.x, a.y, a.z, a.w};
        const float bv[4] = {bb.x, bb.y, bb.z, bb.w};
        int* dw = (int*)dst;
#pragma unroll
        for (int i = 0; i < 4; ++i) {
            const int d = vdg * 4 + i;
            dw[(d * 64 + (vr0 ^ ((d & 7) << 3))) >> 1] = (int)pack2(av[i], bv[i]);
        }
    };

    // prologue for pass A: chunk 0 into buffer 0
    float4 ka, kb;
    loadK(0, ka, kb);
    writeK(shK[0], ka, kb);
    __syncthreads();

    // ---------------- PASS A: row sumexp (fixed C=0), lane-local ----------------
    float lacc = 0.f;
    for (int t = 0; t < NCH; ++t) {
        const int cur = t & 1;
        if (t + 1 < NCH) loadK((t + 1) * 64, ka, kb);   // issue a chunk early
        __syncthreads();                                 // buf[cur] ready
        const short* K = shK[cur];
        const int c0 = t * 64;
        f32x4 s[4] = {{0,0,0,0},{0,0,0,0},{0,0,0,0},{0,0,0,0}};
#pragma unroll
        for (int ct = 0; ct < 4; ++ct) {
            const int kc = ct * 16 + l15;
            bf16x8 kf = ldfrag(&K[SW(kc, 8 * lg)]);
            s[ct] = __builtin_amdgcn_mfma_f32_16x16x32_bf16(kf, qf0, s[ct], 0, 0, 0);
            kf = ldfrag(&K[SW(kc, 32 + 8 * lg)]);
            s[ct] = __builtin_amdgcn_mfma_f32_16x16x32_bf16(kf, qf1, s[ct], 0, 0, 0);
        }
#pragma unroll
        for (int ct = 0; ct < 4; ++ct) {
            const unsigned mw = *(const unsigned*)&shMask[c0 + ct * 16 + lg * 4];
#pragma unroll
            for (int r = 0; r < 4; ++r)
                lacc += ((mw >> (8 * r)) & 1u) ? __expf(s[ct][r]) : 0.f;
        }
        if (t + 1 < NCH) writeK(shK[cur ^ 1], ka, kb);
    }
    lacc += __shfl_xor(lacc, 16);
    lacc += __shfl_xor(lacc, 32);
    const float lnInvl = -__logf(lacc);

    // ---------------- PASS B: recompute, write attn, PV accumulate ----------------
    f32x4 oacc[4] = {{0,0,0,0},{0,0,0,0},{0,0,0,0},{0,0,0,0}};
    float4 va, vb;
    loadK(0, ka, kb);
    loadV(0, va, vb);
    // all waves passed pass-A's last barrier; buf0 reads finished at t=30
    writeK(shK[0], ka, kb);
    writeVt(shVt[0], va, vb);

    float* const shPTw = shPT[w];
    for (int t = 0; t < NCH; ++t) {
        const int cur = t & 1;
        if (t + 1 < NCH) { loadK((t + 1) * 64, ka, kb); loadV((t + 1) * 64, va, vb); }
        __syncthreads();
        const short* K  = shK[cur];
        const short* Vt = shVt[cur];
        const int c0 = t * 64;

        // phase 1: all 4 score tiles (independent chains)
        f32x4 s[4] = {{0,0,0,0},{0,0,0,0},{0,0,0,0},{0,0,0,0}};
#pragma unroll
        for (int ct = 0; ct < 4; ++ct) {
            const int kc = ct * 16 + l15;
            bf16x8 kf = ldfrag(&K[SW(kc, 8 * lg)]);
            s[ct] = __builtin_amdgcn_mfma_f32_16x16x32_bf16(kf, qf0, s[ct], 0, 0, 0);
            kf = ldfrag(&K[SW(kc, 32 + 8 * lg)]);
            s[ct] = __builtin_amdgcn_mfma_f32_16x16x32_bf16(kf, qf1, s[ct], 0, 0, 0);
        }
        // phase 2: exp + mask; stash f32 P to per-wave LDS; pack bf16 p-quads
        s16x4 pf[4];
#pragma unroll
        for (int ct = 0; ct < 4; ++ct) {
            const unsigned mw = *(const unsigned*)&shMask[c0 + ct * 16 + lg * 4];
            f32x4 p;
#pragma unroll
            for (int r = 0; r < 4; ++r)
                p[r] = ((mw >> (8 * r)) & 1u) ? __expf(s[ct][r] + lnInvl) : 0.f;
            *(f32x4*)&shPTw[SWF(l15, ct * 16 + lg * 4)] = p;
            u32x2 pk;
            pk[0] = pack2(p[0], p[1]);
            pk[1] = pack2(p[2], p[3]);
            pf[ct] = __builtin_bit_cast(s16x4, pk);
        }
        // phase 2b: transposed full-line nt stores — 8 lanes x 16B = one whole
        // 128B line per row, 8 rows per instr (no half-line partials at HBM).
#pragma unroll
        for (int st = 0; st < 4; ++st) {
            const int rowIdx = (lane >> 3) + (st >> 1) * 8;
            const int cm     = (lane & 7) * 4 + (st & 1) * 32;
            const f32x4 pv_ = *(const f32x4*)&shPTw[SWF(rowIdx, cm)];
            __builtin_nontemporal_store(
                pv_, (f32x4*)(attnbh + (size_t)(q0 + w * 16 + rowIdx) * S_LEN + c0 + cm));
        }
        // phase 3: PV, 4 independent oacc chains x 4 k-quads (K=16 MFMA)
#pragma unroll
        for (int dt = 0; dt < 4; ++dt) {
#pragma unroll
            for (int ct = 0; ct < 4; ++ct) {
                const s16x4 af = *(const s16x4*)&Vt[SW(dt * 16 + l15, ct * 16 + 4 * lg)];
                oacc[dt] = __builtin_amdgcn_mfma_f32_16x16x16bf16_1k(af, pf[ct], oacc[dt], 0, 0, 0);
            }
        }
        if (t + 1 < NCH) { writeK(shK[cur ^ 1], ka, kb); writeVt(shVt[cur ^ 1], va, vb); }
    }

    // ---- epilogue: out[q][d]; lane holds q=qrow, d = dt*16 + lg*4 + r ----
    float* obase = out + ((size_t)bh * S_LEN + q0 + qrow) * DH;
#pragma unroll
    for (int dt = 0; dt < 4; ++dt)
        __builtin_nontemporal_store(oacc[dt], (f32x4*)(obase + dt * 16 + lg * 4));
}

extern "C" void kernel_launch(void* const* d_in, const int* in_sizes, int n_in,
                              void* d_out, int out_size, void* d_ws, size_t ws_size,
                              hipStream_t stream)
{
    const float* q    = (const float*)d_in[0];
    const float* k    = (const float*)d_in[1];
    const float* v    = (const float*)d_in[2];
    const int*   mask = (const int*)d_in[3];
    float* out  = (float*)d_out;
    float* attn = out + (size_t)2 * 16 * 2048 * 64;   // (out, attn) concatenated

    dim3 grid(S_LEN / QT, 2 * 16);   // R3's 2D grid (x=qtile, y=bh)
    sdpa_kernel<<<grid, dim3(512), 0, stream>>>(q, k, v, mask, out, attn);
}